// Round 2
// baseline (251.240 us; speedup 1.0000x reference)
//
#include <hip/hip_runtime.h>
#include <hip/hip_bf16.h>
#include <stdint.h>

typedef unsigned short ushort_t;
typedef __attribute__((ext_vector_type(4))) float f32x4;
typedef __attribute__((ext_vector_type(8))) __bf16 bf16x8;
typedef __attribute__((ext_vector_type(8))) unsigned short ushort8;
typedef __attribute__((ext_vector_type(4))) unsigned short ushort4v;

__device__ __forceinline__ float bf2f(ushort_t u) {
  union { unsigned u32; float f; } x; x.u32 = ((unsigned)u) << 16; return x.f;
}
__device__ __forceinline__ ushort_t f2bf(float f) {
  union { float f; unsigned u; } x; x.f = f;
  unsigned r = x.u + 0x7FFF + ((x.u >> 16) & 1);
  return (ushort_t)(r >> 16);
}

// async global->LDS, 16 bytes per lane (global_load_lds_dwordx4)
__device__ __forceinline__ void gld16(const ushort_t* g, ushort_t* l) {
  __builtin_amdgcn_global_load_lds(
      (const __attribute__((address_space(1))) uint32_t*)g,
      (__attribute__((address_space(3))) uint32_t*)l, 16, 0, 0);
}

// --- merged cast fp32->bf16 (x,Wq,Wk,Wv) + rowsum zero + OUT zero ---------
// out must be zeroed each run: O-GEMM is split-K and accumulates via
// atomicAdd (also guards against harness output poisoning).
__global__ __launch_bounds__(256) void cast_all_kernel(
    const float* __restrict__ x, const float* __restrict__ wq,
    const float* __restrict__ wk, const float* __restrict__ wv,
    ushort_t* __restrict__ xb, ushort_t* __restrict__ wqb,
    ushort_t* __restrict__ wkb, ushort_t* __restrict__ wvb,
    float* __restrict__ rowsum, float* __restrict__ outz) {
  int blk = blockIdx.x;
  f32x4 z = {0.f, 0.f, 0.f, 0.f};
  if (blk >= 4096 + 1536 + 4) {  // out zero: 4096 blocks x 256 thr x 8 f32
    int idx = (blk - (4096 + 1536 + 4)) * 256 + threadIdx.x;
    ((f32x4*)outz)[idx * 2] = z;
    ((f32x4*)outz)[idx * 2 + 1] = z;
    return;
  }
  if (blk >= 4096 + 1536) {  // rowsum zero: 4 blocks x 256 thr x 8 floats
    int idx = (blk - (4096 + 1536)) * 256 + threadIdx.x;  // 0..1023
    ((f32x4*)rowsum)[idx * 2] = z;
    ((f32x4*)rowsum)[idx * 2 + 1] = z;
    return;
  }
  const float* in;
  ushort_t* out;
  int i;
  if (blk < 4096) {               // x: 8388608 elems = 4096 blocks
    in = x; out = xb; i = blk * 256 + threadIdx.x;
  } else {
    int w = (blk - 4096) >> 9;    // 512 blocks per weight matrix
    int lb = (blk - 4096) & 511;
    in = (w == 0) ? wq : (w == 1) ? wk : wv;
    out = (w == 0) ? wqb : (w == 1) ? wkb : wvb;
    i = lb * 256 + threadIdx.x;
  }
  const f32x4* p = (const f32x4*)in;
  f32x4 a = p[2 * i];
  f32x4 b = p[2 * i + 1];
  ushort8 o;
  o[0] = f2bf(a[0]); o[1] = f2bf(a[1]); o[2] = f2bf(a[2]); o[3] = f2bf(a[3]);
  o[4] = f2bf(b[0]); o[5] = f2bf(b[1]); o[6] = f2bf(b[2]); o[7] = f2bf(b[3]);
  *((ushort8*)out + i) = o;
}

// ============ PROVEN 128x128 core (256 thr, 3 blocks/CU): C = A*B^T =======
// 903 TF regime: implicit cross-block overlap (3 blocks/CU) hides the
// __syncthreads vmcnt drain. XOR k-chunk swizzle on the GLOBAL source
// offset; readers un-swizzle with ln15&7 -> 0 measured bank conflicts.
#define BM 128
#define BN 128
#define BK 64

enum { OUT_EXP = 0, OUT_F32N = 2 };

__device__ __forceinline__ void gemm_core(
    const ushort_t* __restrict__ A, const ushort_t* __restrict__ B, int Kd,
    int kBeg, int kEnd, int m0, int n0, ushort_t* As, ushort_t* Bs,
    f32x4 (&acc)[4][4]) {
  int tid = threadIdx.x;
  int lane = tid & 63;
  int wave = tid >> 6;
  int wr = (wave >> 1) * 64;
  int wc = (wave & 1) * 64;
  int ln15 = lane & 15;
  int kq = lane >> 4;

  int row = tid >> 3;                              // 0..31 (base row of chunk)
  int ksw = ((tid & 7) ^ (row & 7)) * 8;           // swizzled k-offset (elems)
  const ushort_t* aB = A + (size_t)(m0 + row) * Kd + ksw;
  const ushort_t* bB = B + (size_t)(n0 + row) * Kd + ksw;
  int xk = ln15 & 7;                               // reader un-swizzle key

  for (int k0 = kBeg; k0 < kEnd; k0 += BK) {
    __syncthreads();
#pragma unroll
    for (int r = 0; r < 4; ++r) {
      gld16(aB + (size_t)(32 * r) * Kd + k0, &As[(tid + 256 * r) * 8]);
      gld16(bB + (size_t)(32 * r) * Kd + k0, &Bs[(tid + 256 * r) * 8]);
    }
    __syncthreads();
#pragma unroll
    for (int s = 0; s < 2; ++s) {
      bf16x8 af[4], bfr[4];
#pragma unroll
      for (int i = 0; i < 4; ++i)
        af[i] = *(const bf16x8*)
            &As[(wr + i * 16 + ln15) * BK + (((s * 4 + kq) ^ xk) * 8)];
#pragma unroll
      for (int j = 0; j < 4; ++j)
        bfr[j] = *(const bf16x8*)
            &Bs[(wc + j * 16 + ln15) * BK + (((s * 4 + kq) ^ xk) * 8)];
#pragma unroll
      for (int i = 0; i < 4; ++i)
#pragma unroll
        for (int j = 0; j < 4; ++j)
          acc[i][j] = __builtin_amdgcn_mfma_f32_16x16x32_bf16(
              af[i], bfr[j], acc[i][j], 0, 0, 0);
    }
  }
}

// OUT_EXP: S-GEMM fused with softmax numerator (exp w/o max-sub is safe:
// |scores*scale| < ~2.5); bf16 E + fp32 rowsum atomics.
// OUT_F32N: O-GEMM, normalize by 1/rowsum. KCHUNK: split-K into <=1024
// chunks (z = batch*2 + chunk) so all active blocks are uniform (<=34 MF);
// 768 active blocks = exactly 256 CU x 3 blocks/CU -> no long-block tail.
// Partials combine via f32 atomicAdd into pre-zeroed out.
template <int OUT, bool CAUSAL_SKIP, bool K_LIMIT, bool KCHUNK>
__global__ __launch_bounds__(256, 3) void gemm_bt(
    const ushort_t* __restrict__ Ag, const ushort_t* __restrict__ Bg,
    void* __restrict__ Cg, int N, int Kd,
    long sA, long sB, long sC, float scale, float* __restrict__ rowsum) {
  int m0 = blockIdx.x * BM, n0 = blockIdx.y * BN;
  if (CAUSAL_SKIP && n0 > m0 + (BM - 1)) return;
  int bz, kBeg = 0, kEnd;
  if (KCHUNK) {
    bz = blockIdx.z >> 1;
    int kf = K_LIMIT ? min(Kd, m0 + BM) : Kd;
    if (blockIdx.z & 1) {
      if (kf <= 1024) return;  // no second chunk for short rows
      kBeg = 1024; kEnd = kf;
    } else {
      kEnd = min(kf, 1024);
    }
  } else {
    bz = blockIdx.z;
    kEnd = K_LIMIT ? min(Kd, m0 + BM) : Kd;
  }
  const ushort_t* A = Ag + (size_t)bz * sA;
  const ushort_t* B = Bg + (size_t)bz * sB;

  __shared__ ushort_t As[BM * BK];
  __shared__ ushort_t Bs[BN * BK];

  f32x4 acc[4][4];
#pragma unroll
  for (int i = 0; i < 4; ++i)
#pragma unroll
    for (int j = 0; j < 4; ++j) acc[i][j] = f32x4{0.f, 0.f, 0.f, 0.f};

  gemm_core(A, B, Kd, kBeg, kEnd, m0, n0, As, Bs, acc);

  int tid = threadIdx.x;
  int lane = tid & 63;
  int wave = tid >> 6;
  int wr = (wave >> 1) * 64;
  int wc = (wave & 1) * 64;
  int ln15 = lane & 15;
  int kq = lane >> 4;

  // C/D layout (verified m89): col = lane&15, row = (lane>>4)*4 + reg
  if (OUT == OUT_EXP) {
    ushort_t* C = (ushort_t*)Cg + (size_t)bz * sC;
    float* rs = rowsum + (size_t)bz * 2048;
#pragma unroll
    for (int i = 0; i < 4; ++i) {
      int row0 = m0 + wr + i * 16 + kq * 4;
#pragma unroll
      for (int r = 0; r < 4; ++r) {
        int grow = row0 + r;
        float psum = 0.f;
#pragma unroll
        for (int j = 0; j < 4; ++j) {
          int col = n0 + wc + j * 16 + ln15;
          float e = (col <= grow) ? __expf(acc[i][j][r] * scale) : 0.f;
          C[(size_t)grow * N + col] = f2bf(e);
          psum += e;
        }
        // reduce over ln15 (16 lanes share this row's 64-col wave stripe)
        psum += __shfl_xor(psum, 1);
        psum += __shfl_xor(psum, 2);
        psum += __shfl_xor(psum, 4);
        psum += __shfl_xor(psum, 8);
        if (ln15 == 0) atomicAdd(&rs[grow], psum);
      }
    }
  } else {
    float* C = (float*)Cg + (size_t)bz * sC;
    const float* rs = rowsum + (size_t)bz * 2048;
#pragma unroll
    for (int i = 0; i < 4; ++i) {
      int row0 = m0 + wr + i * 16 + kq * 4;
#pragma unroll
      for (int r = 0; r < 4; ++r) {
        float inv = 1.0f / rs[row0 + r];
#pragma unroll
        for (int j = 0; j < 4; ++j) {
          int col = n0 + wc + j * 16 + ln15;
          if (KCHUNK)
            atomicAdd(&C[(size_t)(row0 + r) * N + col], acc[i][j][r] * inv);
          else
            C[(size_t)(row0 + r) * N + col] = acc[i][j][r] * inv;
        }
      }
    }
  }
}

// ============ 256x128 multi-phase core (512 thr) — QKV only ===============
// 8 waves (4M x 2N), per-wave C = 64x64. Phases split by K-HALF (s) so each
// phase is balanced: 8 ds_read_b128 + 3 gld16 + 16 MFMA (R1 had 12+4
// asymmetric windows -> MFMA pipe starved in phase 0). 3-deep LDS rotation,
// counted vmcnt(6) (6 loads/K-tile/wave in flight across barriers, never
// drained in main loop), raw s_barrier, setprio around MFMA cluster.
__device__ __forceinline__ void gemm8_core(
    const ushort_t* __restrict__ A, const ushort_t* __restrict__ B, int Kd,
    int kEnd, int m0, int n0,
    ushort_t* a0, ushort_t* a1, ushort_t* a2,
    ushort_t* b0, ushort_t* b1, ushort_t* b2,
    f32x4 (&acc)[4][4]) {
  int tid = threadIdx.x;
  int lane = tid & 63;
  int wave = tid >> 6;
  int wm = wave >> 1;          // 0..3 -> 64-row stripe
  int wn = wave & 1;           // 0..1 -> 64-col stripe
  int ln15 = lane & 15;
  int kq = lane >> 4;
  int xk = ln15 & 7;           // reader un-swizzle key

  int rowc = tid >> 3;                         // 0..63 (row within 64-chunk)
  int ksw = ((tid & 7) ^ (rowc & 7)) * 8;      // swizzled k-offset (elems)
  const ushort_t* aB = A + (size_t)(m0 + rowc) * Kd + ksw;
  const ushort_t* bB = B + (size_t)(n0 + rowc) * Kd + ksw;

  const int nt = kEnd >> 6;    // K-tiles

  ushort_t *pAr = a0, *pAn = a1, *pAw = a2;
  ushort_t *pBr = b0, *pBn = b1, *pBw = b2;

  // ---- prologue: stage K-tile 0 -> buf0, K-tile 1 -> buf1 (12 loads/thr)
#pragma unroll
  for (int c = 0; c < 4; ++c)
    gld16(aB + (size_t)(64 * c) * Kd, a0 + (size_t)(tid + 512 * c) * 8);
#pragma unroll
  for (int c = 0; c < 2; ++c)
    gld16(bB + (size_t)(64 * c) * Kd, b0 + (size_t)(tid + 512 * c) * 8);
#pragma unroll
  for (int c = 0; c < 4; ++c)
    gld16(aB + (size_t)(64 * c) * Kd + 64, a1 + (size_t)(tid + 512 * c) * 8);
#pragma unroll
  for (int c = 0; c < 2; ++c)
    gld16(bB + (size_t)(64 * c) * Kd + 64, b1 + (size_t)(tid + 512 * c) * 8);
  asm volatile("s_waitcnt vmcnt(6)" ::: "memory");  // K-tile 0 landed
  __builtin_amdgcn_s_barrier();

  for (int t = 0; t < nt; ++t) {
    const bool st = (t + 2) < nt;
    const int k2 = (t + 2) << 6;
    const ushort_t* aT = aB + k2;
    const ushort_t* bT = bB + k2;
    bf16x8 af[4], bf[4];
    // ================= phase 0: k-half s=0 =================
#pragma unroll
    for (int il = 0; il < 4; ++il)
      af[il] = *(const bf16x8*)
          &pAr[(wm * 64 + il * 16 + ln15) * 64 + ((kq ^ xk) * 8)];
#pragma unroll
    for (int j = 0; j < 4; ++j)
      bf[j] = *(const bf16x8*)
          &pBr[(wn * 64 + j * 16 + ln15) * 64 + ((kq ^ xk) * 8)];
    if (st) {  // stage half of K-tile t+2 into the buffer freed at tile t-1
      gld16(aT, pAw + (size_t)tid * 8);
      gld16(aT + (size_t)64 * Kd, pAw + (size_t)(tid + 512) * 8);
      gld16(bT, pBw + (size_t)tid * 8);
    }
    __builtin_amdgcn_s_barrier();
    asm volatile("s_waitcnt lgkmcnt(0)" ::: "memory");
    __builtin_amdgcn_sched_barrier(0);
    __builtin_amdgcn_s_setprio(1);
#pragma unroll
    for (int il = 0; il < 4; ++il)
#pragma unroll
      for (int j = 0; j < 4; ++j)
        acc[il][j] = __builtin_amdgcn_mfma_f32_16x16x32_bf16(
            af[il], bf[j], acc[il][j], 0, 0, 0);
    __builtin_amdgcn_s_setprio(0);
    __builtin_amdgcn_s_barrier();
    // ================= phase 1: k-half s=1 =================
#pragma unroll
    for (int il = 0; il < 4; ++il)
      af[il] = *(const bf16x8*)
          &pAr[(wm * 64 + il * 16 + ln15) * 64 + (((4 + kq) ^ xk) * 8)];
#pragma unroll
    for (int j = 0; j < 4; ++j)
      bf[j] = *(const bf16x8*)
          &pBr[(wn * 64 + j * 16 + ln15) * 64 + (((4 + kq) ^ xk) * 8)];
    if (st) {
      gld16(aT + (size_t)128 * Kd, pAw + (size_t)(tid + 1024) * 8);
      gld16(aT + (size_t)192 * Kd, pAw + (size_t)(tid + 1536) * 8);
      gld16(bT + (size_t)64 * Kd, pBw + (size_t)(tid + 512) * 8);
      // counted wait: leave this tile's 6 loads in flight; tile t+1 landed
      asm volatile("s_waitcnt vmcnt(6)" ::: "memory");
    } else {
      asm volatile("s_waitcnt vmcnt(0)" ::: "memory");  // epilogue drain
    }
    __builtin_amdgcn_s_barrier();
    asm volatile("s_waitcnt lgkmcnt(0)" ::: "memory");
    __builtin_amdgcn_sched_barrier(0);
    __builtin_amdgcn_s_setprio(1);
#pragma unroll
    for (int il = 0; il < 4; ++il)
#pragma unroll
      for (int j = 0; j < 4; ++j)
        acc[il][j] = __builtin_amdgcn_mfma_f32_16x16x32_bf16(
            af[il], bf[j], acc[il][j], 0, 0, 0);
    __builtin_amdgcn_s_setprio(0);
    __builtin_amdgcn_s_barrier();
    // rotate 3-deep buffers: read <- next, next <- written, write <- stale
    ushort_t* tA = pAr; pAr = pAn; pAn = pAw; pAw = tA;
    ushort_t* tB = pBr; pBr = pBn; pBn = pBw; pBw = tB;
  }
}

// merged QKV projection: z=0 -> Q, z=1 -> K, z=2 -> V (transposed per batch)
__global__ __launch_bounds__(512, 2) void gemm_qkv8(
    const ushort_t* __restrict__ xb, const ushort_t* __restrict__ wq,
    const ushort_t* __restrict__ wk, const ushort_t* __restrict__ wv,
    ushort_t* __restrict__ Qb, ushort_t* __restrict__ Kb,
    ushort_t* __restrict__ Vt) {
  int m0 = blockIdx.x * 256, n0 = blockIdx.y * 128;
  int z = blockIdx.z;
  const ushort_t* B = (z == 0) ? wq : (z == 1) ? wk : wv;

  __shared__ ushort_t As[3][256 * 64];
  __shared__ ushort_t Bs[3][128 * 64];

  f32x4 acc[4][4];
#pragma unroll
  for (int i = 0; i < 4; ++i)
#pragma unroll
    for (int j = 0; j < 4; ++j) acc[i][j] = f32x4{0.f, 0.f, 0.f, 0.f};

  gemm8_core(xb, B, 1024, 1024, m0, n0, As[0], As[1], As[2], Bs[0], Bs[1],
             Bs[2], acc);

  int tid = threadIdx.x;
  int lane = tid & 63;
  int wave = tid >> 6;
  int wm = wave >> 1, wn = wave & 1;
  int ln15 = lane & 15, kq = lane >> 4;

  // C/D layout (verified m89): col = lane&15, row = (lane>>4)*4 + reg
  if (z < 2) {
    ushort_t* C = (z == 0) ? Qb : Kb;
#pragma unroll
    for (int i = 0; i < 4; ++i) {
      int row0 = m0 + wm * 64 + i * 16 + kq * 4;
#pragma unroll
      for (int j = 0; j < 4; ++j) {
        int col = n0 + wn * 64 + j * 16 + ln15;
#pragma unroll
        for (int r = 0; r < 4; ++r)
          C[(size_t)(row0 + r) * 1024 + col] = f2bf(acc[i][j][r]);
      }
    }
  } else {
    // V transposed: Vt[b][d][n], token gm -> b = gm>>11, n = gm&2047
#pragma unroll
    for (int i = 0; i < 4; ++i) {
      int gm = m0 + wm * 64 + i * 16 + kq * 4;
      int b = gm >> 11, nn = gm & 2047;
#pragma unroll
      for (int j = 0; j < 4; ++j) {
        int d = n0 + wn * 64 + j * 16 + ln15;
        ushort4v v;
#pragma unroll
        for (int r = 0; r < 4; ++r) v[r] = f2bf(acc[i][j][r]);
        *(ushort4v*)&Vt[(size_t)b * (2048 * 1024) + (size_t)d * 2048 + nn] = v;
      }
    }
  }
}

// ---------------- launch ----------------
extern "C" void kernel_launch(void* const* d_in, const int* in_sizes, int n_in,
                              void* d_out, int out_size, void* d_ws, size_t ws_size,
                              hipStream_t stream) {
  const float* x = (const float*)d_in[0];
  const float* Wq = (const float*)d_in[1];
  const float* Wk = (const float*)d_in[2];
  const float* Wv = (const float*)d_in[3];
  float* out = (float*)d_out;
  char* ws = (char*)d_ws;

  ushort_t* xb = (ushort_t*)(ws);                   // 16 MB
  ushort_t* wqb = (ushort_t*)(ws + (16ull << 20));  // 2 MB
  ushort_t* wkb = (ushort_t*)(ws + (18ull << 20));  // 2 MB
  ushort_t* wvb = (ushort_t*)(ws + (20ull << 20));  // 2 MB
  ushort_t* Qb = (ushort_t*)(ws + (22ull << 20));   // 16 MB
  ushort_t* Kb = (ushort_t*)(ws + (38ull << 20));   // 16 MB
  ushort_t* Vt = (ushort_t*)(ws + (54ull << 20));   // 16 MB (transposed)
  ushort_t* Eb = (ushort_t*)(ws + (70ull << 20));   // 32 MB exp(S) bf16
  float* rowsum = (float*)(ws + (102ull << 20));    // 32 KB fp32

  // cast + rowsum zero + out zero (out is accumulated atomically by O-GEMM)
  cast_all_kernel<<<4096 + 3 * 512 + 4 + 4096, 256, 0, stream>>>(
      x, Wq, Wk, Wv, xb, wqb, wkb, wvb, rowsum, out);

  // QKV: 256x128 multi-phase core; (32,8,3) = 768 blocks = 3 rounds @1/CU
  dim3 gQKV(8192 / 256, 1024 / 128, 3);
  gemm_qkv8<<<gQKV, 512, 0, stream>>>(xb, wqb, wkb, wvb, Qb, Kb, Vt);

  // S-GEMM fused with exp + rowsum atomics (proven 128^2 core, 3 blocks/CU)
  dim3 gS(2048 / BM, 2048 / BN, 4);  // (16, 16, 4), 544 active (causal)
  gemm_bt<OUT_EXP, true, false, false><<<gS, 256, 0, stream>>>(
      Qb, Kb, Eb, 2048, 1024, 2048 * 1024, 2048 * 1024, 2048 * 2048,
      0.03125f, rowsum);

  // O-GEMM: split-K (<=1024 chunks) -> 768 uniform active blocks, f32
  // atomicAdd into zeroed out; normalize by rowsum per chunk (linear).
  dim3 gO(2048 / BM, 1024 / BN, 8);  // (16, 8, 8): z = batch*2 + chunk
  gemm_bt<OUT_F32N, false, true, true><<<gO, 256, 0, stream>>>(
      Eb, Vt, out, 1024, 2048, 2048 * 2048, 1024 * 2048, 2048 * 1024,
      1.0f, rowsum);
}

// Round 3
// 219.647 us; speedup vs baseline: 1.1438x; 1.1438x over previous
//
#include <hip/hip_runtime.h>
#include <hip/hip_bf16.h>
#include <stdint.h>
#include <math.h>

typedef unsigned short ushort_t;
typedef __attribute__((ext_vector_type(4))) float f32x4;
typedef __attribute__((ext_vector_type(8))) __bf16 bf16x8;
typedef __attribute__((ext_vector_type(8))) unsigned short ushort8;
typedef __attribute__((ext_vector_type(4))) unsigned short ushort4v;

__device__ __forceinline__ float bf2f(ushort_t u) {
  union { unsigned u32; float f; } x; x.u32 = ((unsigned)u) << 16; return x.f;
}
__device__ __forceinline__ ushort_t f2bf(float f) {
  union { float f; unsigned u; } x; x.f = f;
  unsigned r = x.u + 0x7FFF + ((x.u >> 16) & 1);
  return (ushort_t)(r >> 16);
}

// async global->LDS, 16 bytes per lane (global_load_lds_dwordx4)
__device__ __forceinline__ void gld16(const ushort_t* g, ushort_t* l) {
  __builtin_amdgcn_global_load_lds(
      (const __attribute__((address_space(1))) uint32_t*)g,
      (__attribute__((address_space(3))) uint32_t*)l, 16, 0, 0);
}

// ------- merged cast fp32->bf16 (x,Wq,Wk,Wv) + rowsum zero (4 blocks) ------
__global__ __launch_bounds__(256) void cast_all_kernel(
    const float* __restrict__ x, const float* __restrict__ wq,
    const float* __restrict__ wk, const float* __restrict__ wv,
    ushort_t* __restrict__ xb, ushort_t* __restrict__ wqb,
    ushort_t* __restrict__ wkb, ushort_t* __restrict__ wvb,
    float* __restrict__ rowsum) {
  int blk = blockIdx.x;
  if (blk >= 4096 + 1536) {  // rowsum zero: 4 blocks x 256 thr x 8 floats
    int idx = (blk - (4096 + 1536)) * 256 + threadIdx.x;  // 0..1023
    f32x4 z = {0.f, 0.f, 0.f, 0.f};
    ((f32x4*)rowsum)[idx * 2] = z;
    ((f32x4*)rowsum)[idx * 2 + 1] = z;
    return;
  }
  const float* in;
  ushort_t* out;
  int i;
  if (blk < 4096) {               // x: 8388608 elems = 4096 blocks
    in = x; out = xb; i = blk * 256 + threadIdx.x;
  } else {
    int w = (blk - 4096) >> 9;    // 512 blocks per weight matrix
    int lb = (blk - 4096) & 511;
    in = (w == 0) ? wq : (w == 1) ? wk : wv;
    out = (w == 0) ? wqb : (w == 1) ? wkb : wvb;
    i = lb * 256 + threadIdx.x;
  }
  const f32x4* p = (const f32x4*)in;
  f32x4 a = p[2 * i];
  f32x4 b = p[2 * i + 1];
  ushort8 o;
  o[0] = f2bf(a[0]); o[1] = f2bf(a[1]); o[2] = f2bf(a[2]); o[3] = f2bf(a[3]);
  o[4] = f2bf(b[0]); o[5] = f2bf(b[1]); o[6] = f2bf(b[2]); o[7] = f2bf(b[3]);
  *((ushort8*)out + i) = o;
}

// ---------------- GEMM tile core: C = A * B^T (PROVEN, 903 TF) -----------
// BK=64: 32 MFMA per barrier pair; 3 blocks/CU implicit overlap hides the
// __syncthreads vmcnt drain. XOR k-chunk swizzle on the GLOBAL source
// offset; readers un-swizzle with ln15&7 -> 0 measured bank conflicts.
#define BM 128
#define BN 128
#define BK 64

enum { OUT_EXP = 0, OUT_F32N = 2 };
enum { MAP_TRI = 0, MAP_PAIR = 1 };

__device__ __forceinline__ void gemm_core(
    const ushort_t* __restrict__ A, const ushort_t* __restrict__ B, int Kd,
    int kEnd, int m0, int n0, ushort_t* As, ushort_t* Bs, f32x4 (&acc)[4][4]) {
  int tid = threadIdx.x;
  int lane = tid & 63;
  int wave = tid >> 6;
  int wr = (wave >> 1) * 64;
  int wc = (wave & 1) * 64;
  int ln15 = lane & 15;
  int kq = lane >> 4;

  int row = tid >> 3;                              // 0..31 (base row of chunk)
  int ksw = ((tid & 7) ^ (row & 7)) * 8;           // swizzled k-offset (elems)
  const ushort_t* aB = A + (size_t)(m0 + row) * Kd + ksw;
  const ushort_t* bB = B + (size_t)(n0 + row) * Kd + ksw;
  int xk = ln15 & 7;                               // reader un-swizzle key

  for (int k0 = 0; k0 < kEnd; k0 += BK) {
    __syncthreads();
#pragma unroll
    for (int r = 0; r < 4; ++r) {
      gld16(aB + (size_t)(32 * r) * Kd + k0, &As[(tid + 256 * r) * 8]);
      gld16(bB + (size_t)(32 * r) * Kd + k0, &Bs[(tid + 256 * r) * 8]);
    }
    __syncthreads();
#pragma unroll
    for (int s = 0; s < 2; ++s) {
      bf16x8 af[4], bfr[4];
#pragma unroll
      for (int i = 0; i < 4; ++i)
        af[i] = *(const bf16x8*)
            &As[(wr + i * 16 + ln15) * BK + (((s * 4 + kq) ^ xk) * 8)];
#pragma unroll
      for (int j = 0; j < 4; ++j)
        bfr[j] = *(const bf16x8*)
            &Bs[(wc + j * 16 + ln15) * BK + (((s * 4 + kq) ^ xk) * 8)];
#pragma unroll
      for (int i = 0; i < 4; ++i)
#pragma unroll
        for (int j = 0; j < 4; ++j)
          acc[i][j] = __builtin_amdgcn_mfma_f32_16x16x32_bf16(
              af[i], bfr[j], acc[i][j], 0, 0, 0);
    }
  }
}

// OUT_EXP + MAP_TRI: S-GEMM fused with softmax numerator, COMPACT causal
//   launch: grid (136,1,4); blockIdx.x is a triangular index decoded to
//   (m,n), n<=m. Spreads 544 active blocks over all 256 CUs (the old
//   (16,16,4) grid put all 4 z-copies of one (x,y) on the SAME CU ->
//   only 136 CUs active, ~39us). exp w/o max-sub safe: |s*scale|<~2.5.
// OUT_F32N + MAP_PAIR: O-GEMM, grid (16,8,4); m = (z<2) ? x : 15-x so the
//   two co-resident blocks on each CU (L and L+256 differ by z+2) have
//   COMPLEMENTARY K (sum const 2304) -> uniform per-CU work (~75.5 MF),
//   kills the double-K=2048-per-CU tail (~40us -> ~25us).
template <int OUT, int MAP>
__global__ __launch_bounds__(256, 3) void gemm_bt(
    const ushort_t* __restrict__ Ag, const ushort_t* __restrict__ Bg,
    void* __restrict__ Cg, int N, int Kd,
    long sA, long sB, long sC, float scale, float* __restrict__ rowsum) {
  int m0, n0, kEnd;
  if (MAP == MAP_TRI) {
    int t = blockIdx.x;  // 0..135 triangular index
    int m = (int)((sqrtf(8.f * (float)t + 1.f) - 1.f) * 0.5f);
    while ((m + 1) * (m + 2) / 2 <= t) ++m;   // guard float edge cases
    while (m * (m + 1) / 2 > t) --m;
    int n = t - m * (m + 1) / 2;              // 0..m
    m0 = m * BM; n0 = n * BN; kEnd = Kd;
  } else {
    int m = (blockIdx.z < 2) ? (int)blockIdx.x
                             : (int)(gridDim.x - 1 - blockIdx.x);
    m0 = m * BM; n0 = blockIdx.y * BN;
    kEnd = min(Kd, m0 + BM);
  }
  int bz = blockIdx.z;
  const ushort_t* A = Ag + (size_t)bz * sA;
  const ushort_t* B = Bg + (size_t)bz * sB;

  __shared__ ushort_t As[BM * BK];
  __shared__ ushort_t Bs[BN * BK];

  f32x4 acc[4][4];
#pragma unroll
  for (int i = 0; i < 4; ++i)
#pragma unroll
    for (int j = 0; j < 4; ++j) acc[i][j] = f32x4{0.f, 0.f, 0.f, 0.f};

  gemm_core(A, B, Kd, kEnd, m0, n0, As, Bs, acc);

  int tid = threadIdx.x;
  int lane = tid & 63;
  int wave = tid >> 6;
  int wr = (wave >> 1) * 64;
  int wc = (wave & 1) * 64;
  int ln15 = lane & 15;
  int kq = lane >> 4;

  // C/D layout (verified m89): col = lane&15, row = (lane>>4)*4 + reg
  if (OUT == OUT_EXP) {
    ushort_t* C = (ushort_t*)Cg + (size_t)bz * sC;
    float* rs = rowsum + (size_t)bz * 2048;
#pragma unroll
    for (int i = 0; i < 4; ++i) {
      int row0 = m0 + wr + i * 16 + kq * 4;
#pragma unroll
      for (int r = 0; r < 4; ++r) {
        int grow = row0 + r;
        float psum = 0.f;
#pragma unroll
        for (int j = 0; j < 4; ++j) {
          int col = n0 + wc + j * 16 + ln15;
          float e = (col <= grow) ? __expf(acc[i][j][r] * scale) : 0.f;
          C[(size_t)grow * N + col] = f2bf(e);
          psum += e;
        }
        // reduce over ln15 (16 lanes share this row's 64-col wave stripe)
        psum += __shfl_xor(psum, 1);
        psum += __shfl_xor(psum, 2);
        psum += __shfl_xor(psum, 4);
        psum += __shfl_xor(psum, 8);
        if (ln15 == 0) atomicAdd(&rs[grow], psum);
      }
    }
  } else {
    float* C = (float*)Cg + (size_t)bz * sC;
    const float* rs = rowsum + (size_t)bz * 2048;
#pragma unroll
    for (int i = 0; i < 4; ++i) {
      int row0 = m0 + wr + i * 16 + kq * 4;
#pragma unroll
      for (int r = 0; r < 4; ++r) {
        float inv = 1.0f / rs[row0 + r];
#pragma unroll
        for (int j = 0; j < 4; ++j) {
          int col = n0 + wc + j * 16 + ln15;
          C[(size_t)(row0 + r) * N + col] = acc[i][j][r] * inv;
        }
      }
    }
  }
}

// merged QKV projection: z=0 -> Q, z=1 -> K, z=2 -> V (transposed per batch)
__global__ __launch_bounds__(256, 3) void gemm_qkv(
    const ushort_t* __restrict__ xb, const ushort_t* __restrict__ wq,
    const ushort_t* __restrict__ wk, const ushort_t* __restrict__ wv,
    ushort_t* __restrict__ Qb, ushort_t* __restrict__ Kb,
    ushort_t* __restrict__ Vt) {
  int m0 = blockIdx.x * BM, n0 = blockIdx.y * BN;
  int z = blockIdx.z;
  const ushort_t* B = (z == 0) ? wq : (z == 1) ? wk : wv;

  __shared__ ushort_t As[BM * BK];
  __shared__ ushort_t Bs[BN * BK];

  f32x4 acc[4][4];
#pragma unroll
  for (int i = 0; i < 4; ++i)
#pragma unroll
    for (int j = 0; j < 4; ++j) acc[i][j] = f32x4{0.f, 0.f, 0.f, 0.f};

  gemm_core(xb, B, 1024, 1024, m0, n0, As, Bs, acc);

  int tid = threadIdx.x;
  int lane = tid & 63;
  int wave = tid >> 6;
  int wr = (wave >> 1) * 64;
  int wc = (wave & 1) * 64;
  int ln15 = lane & 15;
  int kq = lane >> 4;

  if (z < 2) {
    ushort_t* C = (z == 0) ? Qb : Kb;
#pragma unroll
    for (int i = 0; i < 4; ++i) {
      int row0 = m0 + wr + i * 16 + kq * 4;
#pragma unroll
      for (int j = 0; j < 4; ++j) {
        int col = n0 + wc + j * 16 + ln15;
#pragma unroll
        for (int r = 0; r < 4; ++r)
          C[(size_t)(row0 + r) * 1024 + col] = f2bf(acc[i][j][r]);
      }
    }
  } else {
    // V transposed: Vt[b][d][n], token gm -> b = gm>>11, n = gm&2047
#pragma unroll
    for (int i = 0; i < 4; ++i) {
      int gm = m0 + wr + i * 16 + kq * 4;
      int b = gm >> 11, nn = gm & 2047;
#pragma unroll
      for (int j = 0; j < 4; ++j) {
        int d = n0 + wc + j * 16 + ln15;
        ushort4v v;
#pragma unroll
        for (int r = 0; r < 4; ++r) v[r] = f2bf(acc[i][j][r]);
        *(ushort4v*)&Vt[(size_t)b * (2048 * 1024) + (size_t)d * 2048 + nn] = v;
      }
    }
  }
}

// ---------------- launch ----------------
extern "C" void kernel_launch(void* const* d_in, const int* in_sizes, int n_in,
                              void* d_out, int out_size, void* d_ws, size_t ws_size,
                              hipStream_t stream) {
  const float* x = (const float*)d_in[0];
  const float* Wq = (const float*)d_in[1];
  const float* Wk = (const float*)d_in[2];
  const float* Wv = (const float*)d_in[3];
  float* out = (float*)d_out;
  char* ws = (char*)d_ws;

  ushort_t* xb = (ushort_t*)(ws);                   // 16 MB
  ushort_t* wqb = (ushort_t*)(ws + (16ull << 20));  // 2 MB
  ushort_t* wkb = (ushort_t*)(ws + (18ull << 20));  // 2 MB
  ushort_t* wvb = (ushort_t*)(ws + (20ull << 20));  // 2 MB
  ushort_t* Qb = (ushort_t*)(ws + (22ull << 20));   // 16 MB
  ushort_t* Kb = (ushort_t*)(ws + (38ull << 20));   // 16 MB
  ushort_t* Vt = (ushort_t*)(ws + (54ull << 20));   // 16 MB (transposed)
  ushort_t* Eb = (ushort_t*)(ws + (70ull << 20));   // 32 MB exp(S) bf16
  float* rowsum = (float*)(ws + (102ull << 20));    // 32 KB fp32

  cast_all_kernel<<<4096 + 3 * 512 + 4, 256, 0, stream>>>(
      x, Wq, Wk, Wv, xb, wqb, wkb, wvb, rowsum);

  dim3 gQKV(8192 / BM, 1024 / BN, 3);  // (64, 8, 3)
  gemm_qkv<<<gQKV, 256, 0, stream>>>(xb, wqb, wkb, wvb, Qb, Kb, Vt);

  // S-GEMM fused with exp + rowsum atomics; compact triangular launch:
  // 136 active (m,n) tiles per batch, 544 blocks total over all 256 CUs
  dim3 gS(136, 1, 4);
  gemm_bt<OUT_EXP, MAP_TRI><<<gS, 256, 0, stream>>>(
      Qb, Kb, Eb, 2048, 1024, 2048 * 1024, 2048 * 1024, 2048 * 2048,
      0.03125f, rowsum);

  // O-GEMM: complementary-K pairing (z<2: m=x, z>=2: m=15-x) -> uniform
  // per-CU work; normalize by rowsum in epilogue
  dim3 gO(2048 / BM, 1024 / BN, 4);  // (16, 8, 4)
  gemm_bt<OUT_F32N, MAP_PAIR><<<gO, 256, 0, stream>>>(
      Eb, Vt, out, 1024, 2048, 2048 * 2048, 1024 * 2048, 2048 * 1024,
      1.0f, rowsum);
}